// Round 6
// baseline (229.403 us; speedup 1.0000x reference)
//
#include <hip/hip_runtime.h>

// EIT3Attention: B=4, Sq=Sk=2048, d_model=2048, H=16, Dh=128, fp32 I/O.
// R6 = R5 structure (4-wave/256-thr blocks, q-tile 128, KVB=32, grid 1024,
// prepass bf16 ws, global_load_lds dbuf, defer-max) with the R5 bug fixed:
// pair reductions back to __shfl_xor(x,32). R5's permlane pair-reduce fed
// two IDENTICAL-valued "+v" operands to v_permlane32_swap -> compiler
// coalesced them into one VGPR -> degenerate swap -> wrong L (absmax 1.5e-2).

typedef __attribute__((ext_vector_type(8))) short short8;
typedef __attribute__((ext_vector_type(16))) float f32x16;

#define DEVI __device__ __forceinline__

namespace {

constexpr int DM = 2048;   // d_model
constexpr int SQ = 2048;
constexpr int SK = 2048;
constexpr int DH = 128;
constexpr int KVB = 32;            // kv rows per tile
constexpr int NT = SK / KVB;       // 64 tiles
constexpr int TILE_E = KVB * DH;   // 4096 elems per tensor-tile
// (1/sqrt(128)) * log2(e)
constexpr float CEXP = 0.12752051393f;
constexpr float DEFER = 62.0f;     // raw-score defer threshold (~e^7.9 bound)

union US8 { unsigned short u[8]; short8 v; };
union UP4 { unsigned int u[4]; short8 v; };

DEVI unsigned short f2bf(float f) {            // fp32 -> bf16 RNE
  unsigned int u = __float_as_uint(f);
  return (unsigned short)((u + 0x7fffu + ((u >> 16) & 1u)) >> 16);
}

DEVI float dq(float x) {                       // int4 quant-dequant, matches ref
  float t = __builtin_rintf(__builtin_fmaf(x, 20.0f, 8.0f));  // round half-even
  t = __builtin_fmaxf(t, 0.0f);
  t = __builtin_fminf(t, 15.0f);
  return (t - 8.0f) * 0.05f;
}

DEVI unsigned short dqb(float x) { return f2bf(dq(x)); }

} // namespace

// ---------------------------------------------------------------------------
// Prepass (verified R2/R3): dequant K/V -> bf16 ws, one (b,h,32-row-tile)/block.
// K ws tile: elem u = (n*128 + d) ^ ((n&7)<<3)            [n=0..31, d=0..127]
// V ws tile: transposed, elem u = d*32 + (k ^ (((d>>1)&3)<<3))    [k=0..31]
// Both are the exact linear LDS images the main kernel stages + reads.
// ---------------------------------------------------------------------------
__global__ __launch_bounds__(512)
void eit3_pre(const float* __restrict__ kg, const float* __restrict__ vg,
              unsigned short* __restrict__ kws, unsigned short* __restrict__ vws)
{
  const int tid = threadIdx.x;
  const int t = blockIdx.x, h = blockIdx.y, b = blockIdx.z;
  const size_t tb = (((size_t)(b * 16 + h)) * NT + t) * TILE_E;
  // V transpose staging: stride 132 elems; granule col of (r,*) ^= ((r>>3)&3)
  __shared__ __align__(16) unsigned short VL[32 * 132];

  // ---- K: dest-driven (swizzle is self-inverse on the d field) ----
  {
    const int g = tid;                      // 512 granules of 8 elems
    const int n = g >> 4;
    const int dsw = ((g & 15) * 8) ^ ((n & 7) << 3);
    const float* src = kg + ((size_t)b * SK + (size_t)t * KVB + n) * DM + h * DH + dsw;
    float4 fa = *(const float4*)src;
    float4 fb = *(const float4*)(src + 4);
    US8 o;
    o.u[0] = dqb(fa.x); o.u[1] = dqb(fa.y); o.u[2] = dqb(fa.z); o.u[3] = dqb(fa.w);
    o.u[4] = dqb(fb.x); o.u[5] = dqb(fb.y); o.u[6] = dqb(fb.z); o.u[7] = dqb(fb.w);
    *(short8*)(kws + tb + (size_t)g * 8) = o.v;
  }
  // ---- V rows -> LDS (dequant, coalesced read, swizzled column granule) ----
  {
    const int r = tid >> 4, dg = tid & 15;
    const float* src = vg + ((size_t)b * SK + (size_t)t * KVB + r) * DM + h * DH + dg * 8;
    float4 fa = *(const float4*)src;
    float4 fb = *(const float4*)(src + 4);
    US8 o;
    o.u[0] = dqb(fa.x); o.u[1] = dqb(fa.y); o.u[2] = dqb(fa.z); o.u[3] = dqb(fa.w);
    o.u[4] = dqb(fb.x); o.u[5] = dqb(fb.y); o.u[6] = dqb(fb.z); o.u[7] = dqb(fb.w);
    *(short8*)(VL + r * 132 + (dg ^ ((r >> 3) & 3)) * 8) = o.v;
  }
  __syncthreads();
  // ---- V^T: dest-driven transpose out of LDS, coalesced 16B ws writes ----
  {
    const int g2 = tid;                 // dest granules [g2*8, g2*8+8)
    const int d = g2 >> 2;
    const int kgr = (g2 & 3) ^ ((d >> 1) & 3);
    US8 o;
#pragma unroll
    for (int i = 0; i < 8; ++i) {
      int r = kgr * 8 + i;
      o.u[i] = VL[r * 132 + (d ^ (kgr * 8))];
    }
    *(short8*)(vws + tb + (size_t)g2 * 8) = o.v;
  }
}

// ---------------------------------------------------------------------------
// Main attention kernel: 4 waves, 32 q-rows/wave, KVB=32, double-buffered.
// ---------------------------------------------------------------------------
__global__ __launch_bounds__(256, 2)
void eit3_attn(const unsigned short* __restrict__ kws,
               const unsigned short* __restrict__ vws,
               const float* __restrict__ qg,
               const unsigned char* __restrict__ maskg,
               const int* __restrict__ qsg, float* __restrict__ outg)
{
  const int tid  = threadIdx.x;
  const int lane = tid & 63;
  const int w    = tid >> 6;        // wave 0..3
  const int hi   = lane >> 5;
  const int ql   = lane & 31;
  const int hi8  = hi * 8;
  // XCD-grouped decode: XCD x owns bh in {8g+x}; 16 q-blocks of a bh + 8 bh
  // co-located per XCD -> ws streams are L2 hits after first touch.
  const int phys = blockIdx.x;                     // 0..1023
  const int xcd = phys & 7, slot = phys >> 3;      // slot 0..127
  const int bh = 8 * (slot >> 4) + xcd;            // 0..63
  const int qb = slot & 15;                        // 0..15
  const int h = bh & 15, b = bh >> 4;
  const int q0 = qb * 128;
  const long long qstart = (long long)qsg[0];

  __shared__ __align__(16) unsigned short Ksh[2][TILE_E];
  __shared__ __align__(16) unsigned short Vsh[2][TILE_E];
  __shared__ unsigned char mskSh[2][32];

  // ---- robust all-true mask check (u8 or i32 bool layouts), 8 B/thread ----
  const unsigned char* mrow = maskg + (size_t)b * SK;
  int ok_u8, ok_i32;
  {
    const unsigned int* p = (const unsigned int*)(mrow + tid * 8);
    unsigned int w0 = p[0], w1 = p[1];
    int a0 = (w0 & 0xFFu) && (w0 & 0xFF00u) && (w0 & 0xFF0000u) && (w0 & 0xFF000000u);
    int a1 = (w1 & 0xFFu) && (w1 & 0xFF00u) && (w1 & 0xFF0000u) && (w1 & 0xFF000000u);
    ok_u8  = a0 && a1;
    ok_i32 = (w0 == 1u) && (w1 == 1u);
  }
  const int a_u8  = __syncthreads_and(ok_u8);
  const int a_i32 = __syncthreads_and(ok_i32);
  const bool mask_all = (a_u8 | a_i32) != 0;

  const size_t tbase = (size_t)bh * NT * TILE_E;

  // stage tile t into buffer buf: 1 KiB per wave per tensor = 2 gll each
  auto stage = [&](int buf, int t) {
    const unsigned short* kt = kws + tbase + (size_t)t * TILE_E + w * 1024 + lane * 8;
    const unsigned short* vt = vws + tbase + (size_t)t * TILE_E + w * 1024 + lane * 8;
    char* kd = (char*)&Ksh[0][0] + buf * 8192 + w * 2048;
    char* vd = (char*)&Vsh[0][0] + buf * 8192 + w * 2048;
    __builtin_amdgcn_global_load_lds(
        (const __attribute__((address_space(1))) void*)kt,
        (__attribute__((address_space(3))) void*)kd, 16, 0, 0);
    __builtin_amdgcn_global_load_lds(
        (const __attribute__((address_space(1))) void*)(kt + 512),
        (__attribute__((address_space(3))) void*)(kd + 1024), 16, 0, 0);
    __builtin_amdgcn_global_load_lds(
        (const __attribute__((address_space(1))) void*)vt,
        (__attribute__((address_space(3))) void*)vd, 16, 0, 0);
    __builtin_amdgcn_global_load_lds(
        (const __attribute__((address_space(1))) void*)(vt + 512),
        (__attribute__((address_space(3))) void*)(vd + 1024), 16, 0, 0);
  };

  stage(0, 0);   // issue first-tile staging before Q loads

  // ---- Q fragments (B-operand of swapped QK^T): lane holds Q[q][16s+8hi+i] ----
  short8 qf[8];
  {
    const float* qp = qg + ((size_t)b * SQ + q0 + w * 32 + ql) * DM + h * DH + hi8;
#pragma unroll
    for (int s = 0; s < 8; ++s) {
      float4 fa = *(const float4*)(qp + s * 16);
      float4 fb = *(const float4*)(qp + s * 16 + 4);
      US8 t;
      t.u[0] = f2bf(fa.x); t.u[1] = f2bf(fa.y); t.u[2] = f2bf(fa.z); t.u[3] = f2bf(fa.w);
      t.u[4] = f2bf(fb.x); t.u[5] = f2bf(fb.y); t.u[6] = f2bf(fb.z); t.u[7] = f2bf(fb.w);
      qf[s] = t.v;
    }
  }

  f32x16 zv;
#pragma unroll
  for (int r = 0; r < 16; ++r) zv[r] = 0.0f;
  f32x16 acc[4];
  acc[0] = zv; acc[1] = zv; acc[2] = zv; acc[3] = zv;
  float M = -3.0e38f, L = 0.0f;
  const long long qlim = qstart + (long long)(q0 + w * 32 + ql);

  {
    bool f0 = mask_all && ((long long)(KVB - 1) <= qstart + (long long)q0);
    if (!f0 && w == 0 && lane < 32) mskSh[0][lane] = mrow[lane];
  }
  __syncthreads();   // drains stage(0) vmcnt

  int cur = 0;
  for (int ti = 0; ti < NT; ++ti) {
    const int kv0 = ti * KVB;
    const int nxt = cur ^ 1;
    if (ti + 1 < NT) {
      stage(nxt, ti + 1);
      bool fn = mask_all && ((long long)(kv0 + 2 * KVB - 1) <= qstart + (long long)q0);
      if (!fn && w == 0 && lane < 32) mskSh[nxt][lane] = mrow[kv0 + KVB + lane];
    }
    const bool fast = mask_all && ((long long)(kv0 + KVB - 1) <= qstart + (long long)q0);

    const unsigned short* Kc = &Ksh[cur][0];
    const unsigned short* Vc = &Vsh[cur][0];

    // ---- QK^T (swapped): S^T[k][q] = Kd[k][:]·Q[q][:], k = 0..31 ----
    f32x16 st = zv;
    __builtin_amdgcn_s_setprio(1);
#pragma unroll
    for (int s = 0; s < 8; ++s) {
      short8 af = *(const short8*)(Kc + ql * 128 + ((s * 16 + hi8) ^ ((ql & 7) << 3)));
      st = __builtin_amdgcn_mfma_f32_32x32x16_bf16(af, qf[s], st, 0, 0, 0);
    }
    __builtin_amdgcn_s_setprio(0);

    // ---- masking (slow path only) ----
    if (!fast) {
#pragma unroll
      for (int r = 0; r < 16; ++r) {
        int nl = (r & 3) + 8 * (r >> 2) + 4 * hi;
        bool ok = (mskSh[cur][nl] != 0) && ((long long)(kv0 + nl) <= qlim);
        if (!ok) st[r] = -3.0e38f;
      }
    }

    // ---- online softmax (defer-max); verified shfl_xor pair reduce ----
    float t8[8];
#pragma unroll
    for (int i = 0; i < 8; ++i) t8[i] = __builtin_fmaxf(st[i], st[i + 8]);
#pragma unroll
    for (int i = 0; i < 4; ++i) t8[i] = __builtin_fmaxf(t8[i], t8[i + 4]);
    float pmax = __builtin_fmaxf(__builtin_fmaxf(t8[0], t8[1]),
                                 __builtin_fmaxf(t8[2], t8[3]));
    pmax = __builtin_fmaxf(pmax, __shfl_xor(pmax, 32));
    if (!__all(pmax <= M + DEFER)) {        // T13: rescale only on real growth
      float Mn = __builtin_fmaxf(M, pmax);
      float sc = __builtin_amdgcn_exp2f((M - Mn) * CEXP);
      L *= sc;
#pragma unroll
      for (int r = 0; r < 16; ++r) {
        float s2 = __shfl(sc, (r & 3) + 8 * (r >> 2) + 4 * hi);
        acc[0][r] *= s2; acc[1][r] *= s2; acc[2][r] *= s2; acc[3][r] *= s2;
      }
      M = Mn;
    }
#pragma unroll
    for (int r = 0; r < 16; ++r)
      st[r] = __builtin_amdgcn_exp2f((st[r] - M) * CEXP);
    if (!fast) {   // force masked p to exactly 0 (handles all-masked tiles)
#pragma unroll
      for (int r = 0; r < 16; ++r) {
        int nl = (r & 3) + 8 * (r >> 2) + 4 * hi;
        bool ok = (mskSh[cur][nl] != 0) && ((long long)(kv0 + nl) <= qlim);
        if (!ok) st[r] = 0.0f;
      }
    }
    float s8[8];
#pragma unroll
    for (int i = 0; i < 8; ++i) s8[i] = st[i] + st[i + 8];
#pragma unroll
    for (int i = 0; i < 4; ++i) s8[i] = s8[i] + s8[i + 4];
    float ps = (s8[0] + s8[1]) + (s8[2] + s8[3]);
    ps += __shfl_xor(ps, 32);
    L += ps;

    // ---- P -> bf16 A-frags: cvt_pk pairs + permlane32_swap (T12) ----
    // (safe: X*/Y* hold DISTINCT values, no register-coalescing hazard)
    short8 pa[2];
#pragma unroll
    for (int ks = 0; ks < 2; ++ks) {
      const int m8 = ks * 8;
      unsigned int X0, X1, Y0, Y1;
      asm("v_cvt_pk_bf16_f32 %0, %1, %2" : "=v"(X0) : "v"(st[m8 + 0]), "v"(st[m8 + 1]));
      asm("v_cvt_pk_bf16_f32 %0, %1, %2" : "=v"(X1) : "v"(st[m8 + 2]), "v"(st[m8 + 3]));
      asm("v_cvt_pk_bf16_f32 %0, %1, %2" : "=v"(Y0) : "v"(st[m8 + 4]), "v"(st[m8 + 5]));
      asm("v_cvt_pk_bf16_f32 %0, %1, %2" : "=v"(Y1) : "v"(st[m8 + 6]), "v"(st[m8 + 7]));
      asm("v_permlane32_swap_b32 %0, %1" : "+v"(X0), "+v"(Y0));
      asm("v_permlane32_swap_b32 %0, %1" : "+v"(X1), "+v"(Y1));
      UP4 P;
      P.u[0] = X0; P.u[1] = X1; P.u[2] = Y0; P.u[3] = Y1;
      pa[ks] = P.v;
    }

    // ---- PV: out[q][d] += P[q][k]·Vd[k][d]; B-frag from V^T LDS ----
    __builtin_amdgcn_s_setprio(1);
#pragma unroll
    for (int n = 0; n < 4; ++n) {
      const unsigned short* vrow = Vc + n * 1024 + ql * 32;
#pragma unroll
      for (int ks = 0; ks < 2; ++ks) {
        short8 vb = *(const short8*)(vrow + ((ks * 16 + hi8) ^ (((ql >> 1) & 3) << 3)));
        acc[n] = __builtin_amdgcn_mfma_f32_32x32x16_bf16(pa[ks], vb, acc[n], 0, 0, 0);
      }
    }
    __builtin_amdgcn_s_setprio(0);

    __syncthreads();   // all reads of cur done + prefetch vmcnt drained
    cur = nxt;
  }

  // ---- epilogue: out = acc / L ----
  if (L == 0.0f) L = 1.0f;
  float rinv = 1.0f / L;
#pragma unroll
  for (int r = 0; r < 16; ++r) {
    int cr = (r & 3) + 8 * (r >> 2) + 4 * hi;
    float inv = __shfl(rinv, cr);
    float* op = outg + ((size_t)b * SQ + q0 + w * 32 + cr) * DM + h * DH + ql;
    op[0]  = acc[0][r] * inv;
    op[32] = acc[1][r] * inv;
    op[64] = acc[2][r] * inv;
    op[96] = acc[3][r] * inv;
  }
}

// ---------------------------------------------------------------------------
// Fallback (R1 kernel, in-kernel dequant) — used only if ws is too small.
// ---------------------------------------------------------------------------
__global__ __launch_bounds__(512, 2)
void eit3_attn_fb(const float* __restrict__ qg, const float* __restrict__ kg,
                  const float* __restrict__ vg, const unsigned char* __restrict__ maskg,
                  const int* __restrict__ qsg, float* __restrict__ outg)
{
  const int tid  = threadIdx.x;
  const int lane = tid & 63;
  const int w    = tid >> 6;
  const int hi   = lane >> 5;
  const int ql   = lane & 31;
  const int qb = blockIdx.x;
  const int h  = blockIdx.y;
  const int b  = blockIdx.z;
  const int q0 = qb * 256;
  const long long qstart = (long long)qsg[0];

  __shared__ __align__(16) unsigned short Ksh[64 * 128];
  __shared__ __align__(16) unsigned short Vsh[64 * 128];
  __shared__ unsigned char mskSh[64];

  const unsigned int vbase = (unsigned int)(size_t)(void*)Vsh;

  const unsigned char* mrow = maskg + (size_t)b * SK;
  int ok_u8, ok_i32;
  {
    const unsigned char* p4 = mrow + tid * 4;
    unsigned char b0 = p4[0], b1 = p4[1], b2 = p4[2], b3 = p4[3];
    ok_u8  = (b0 && b1 && b2 && b3);
    ok_i32 = (b0 && !b1 && !b2 && !b3);
  }
  const int a_u8  = __syncthreads_and(ok_u8);
  const int a_i32 = __syncthreads_and(ok_i32);
  const bool mask_all = (a_u8 | a_i32) != 0;

  short8 qf[8];
  {
    const int qrow = q0 + w * 32 + ql;
    const float* qp = qg + ((size_t)b * SQ + qrow) * DM + h * DH + hi * 8;
#pragma unroll
    for (int s = 0; s < 8; ++s) {
      float4 fa = *(const float4*)(qp + s * 16);
      float4 fb = *(const float4*)(qp + s * 16 + 4);
      US8 t;
      t.u[0] = f2bf(fa.x); t.u[1] = f2bf(fa.y); t.u[2] = f2bf(fa.z); t.u[3] = f2bf(fa.w);
      t.u[4] = f2bf(fb.x); t.u[5] = f2bf(fb.y); t.u[6] = f2bf(fb.z); t.u[7] = f2bf(fb.w);
      qf[s] = t.v;
    }
  }

  f32x16 zv;
#pragma unroll
  for (int r = 0; r < 16; ++r) zv[r] = 0.0f;
  f32x16 acc[4];
  acc[0] = zv; acc[1] = zv; acc[2] = zv; acc[3] = zv;
  float M = -3.0e38f, L = 0.0f;

  const float* kptr = kg + ((size_t)b * SK) * DM + h * DH;
  const float* vptr = vg + ((size_t)b * SK) * DM + h * DH;

  for (int kv0 = 0; kv0 < SK; kv0 += 64) {
    __syncthreads();
#pragma unroll
    for (int j = 0; j < 2; ++j) {
      int idx = tid + 512 * j;
      int n = idx >> 4, d8 = idx & 15;
      const float* gp = kptr + (size_t)(kv0 + n) * DM + d8 * 8;
      float4 fa = *(const float4*)gp;
      float4 fb = *(const float4*)(gp + 4);
      US8 t;
      t.u[0] = dqb(fa.x); t.u[1] = dqb(fa.y); t.u[2] = dqb(fa.z); t.u[3] = dqb(fa.w);
      t.u[4] = dqb(fb.x); t.u[5] = dqb(fb.y); t.u[6] = dqb(fb.z); t.u[7] = dqb(fb.w);
      int ui = (n * 128 + d8 * 8) ^ ((n & 7) << 3);
      *(short8*)(Ksh + ui) = t.v;
    }
    {
      int kr = w * 8 + (lane & 7);
      int c3 = lane >> 3;
#pragma unroll
      for (int j = 0; j < 4; ++j) {
        int d4 = c3 + 8 * j;
        const float* gp = vptr + (size_t)(kv0 + kr) * DM + d4 * 4;
        float4 fa = *(const float4*)gp;
        ushort4 tv;
        tv.x = dqb(fa.x); tv.y = dqb(fa.y); tv.z = dqb(fa.z); tv.w = dqb(fa.w);
        int d = d4 * 4;
        int ui = ((kr >> 2) * 8 + (d >> 4)) * 64 + (kr & 3) * 16 + (d & 15);
        *(ushort4*)(Vsh + ui) = tv;
      }
    }
    const bool causal_ok = ((long long)kv0 + 63) <= (qstart + (long long)q0);
    const bool fast = mask_all && causal_ok;
    if (!fast && w == 0) mskSh[lane] = mrow[kv0 + lane];
    __syncthreads();

    f32x16 st[2];
#pragma unroll
    for (int t = 0; t < 2; ++t) {
      f32x16 sa = zv;
#pragma unroll
      for (int s = 0; s < 8; ++s) {
        int kr = t * 32 + ql;
        int ui = (kr * 128 + s * 16 + hi * 8) ^ ((kr & 7) << 3);
        short8 af = *(const short8*)(Ksh + ui);
        sa = __builtin_amdgcn_mfma_f32_32x32x16_bf16(af, qf[s], sa, 0, 0, 0);
      }
      st[t] = sa;
    }
    if (!fast) {
      const long long qlim = qstart + (long long)(q0 + w * 32 + ql);
#pragma unroll
      for (int t = 0; t < 2; ++t) {
#pragma unroll
        for (int r = 0; r < 16; ++r) {
          int nl = t * 32 + (r & 3) + 8 * (r >> 2) + 4 * hi;
          bool ok = (mskSh[nl] != 0) && ((long long)(kv0 + nl) <= qlim);
          if (!ok) st[t][r] = -3.0e38f;
        }
      }
    }
    f32x16 red;
#pragma unroll
    for (int r = 0; r < 16; ++r) red[r] = __builtin_fmaxf(st[0][r], st[1][r]);
#pragma unroll
    for (int r = 0; r < 8; ++r) red[r] = __builtin_fmaxf(red[r], red[r + 8]);
#pragma unroll
    for (int r = 0; r < 4; ++r) red[r] = __builtin_fmaxf(red[r], red[r + 4]);
    float pmax = __builtin_fmaxf(__builtin_fmaxf(red[0], red[1]),
                                 __builtin_fmaxf(red[2], red[3]));
    pmax = __builtin_fmaxf(pmax, __shfl_xor(pmax, 32));
    const float Mnew = __builtin_fmaxf(M, pmax);
    const float scale = __builtin_amdgcn_exp2f((M - Mnew) * CEXP);
#pragma unroll
    for (int t = 0; t < 2; ++t) {
#pragma unroll
      for (int r = 0; r < 16; ++r)
        st[t][r] = __builtin_amdgcn_exp2f((st[t][r] - Mnew) * CEXP);
    }
    if (!fast) {
      const long long qlim = qstart + (long long)(q0 + w * 32 + ql);
#pragma unroll
      for (int t = 0; t < 2; ++t) {
#pragma unroll
        for (int r = 0; r < 16; ++r) {
          int nl = t * 32 + (r & 3) + 8 * (r >> 2) + 4 * hi;
          bool ok = (mskSh[nl] != 0) && ((long long)(kv0 + nl) <= qlim);
          if (!ok) st[t][r] = 0.0f;
        }
      }
    }
    f32x16 sx;
#pragma unroll
    for (int r = 0; r < 16; ++r) sx[r] = st[0][r] + st[1][r];
#pragma unroll
    for (int r = 0; r < 8; ++r) sx[r] = sx[r] + sx[r + 8];
#pragma unroll
    for (int r = 0; r < 4; ++r) sx[r] = sx[r] + sx[r + 4];
    float ps = (sx[0] + sx[1]) + (sx[2] + sx[3]);
    ps += __shfl_xor(ps, 32);
    L = L * scale + ps;
    if (!__all(Mnew == M)) {
#pragma unroll
      for (int r = 0; r < 16; ++r) {
        float sc = __shfl(scale, (r & 3) + 8 * (r >> 2) + 4 * hi);
        acc[0][r] *= sc; acc[1][r] *= sc; acc[2][r] *= sc; acc[3][r] *= sc;
      }
    }
    M = Mnew;

    short8 pa[4];
#pragma unroll
    for (int ks = 0; ks < 4; ++ks) {
      const int t = ks >> 1;
      const int m8 = (ks & 1) * 8;
      unsigned int X0, X1, Y0, Y1;
      asm("v_cvt_pk_bf16_f32 %0, %1, %2" : "=v"(X0) : "v"(st[t][m8 + 0]), "v"(st[t][m8 + 1]));
      asm("v_cvt_pk_bf16_f32 %0, %1, %2" : "=v"(X1) : "v"(st[t][m8 + 2]), "v"(st[t][m8 + 3]));
      asm("v_cvt_pk_bf16_f32 %0, %1, %2" : "=v"(Y0) : "v"(st[t][m8 + 4]), "v"(st[t][m8 + 5]));
      asm("v_cvt_pk_bf16_f32 %0, %1, %2" : "=v"(Y1) : "v"(st[t][m8 + 6]), "v"(st[t][m8 + 7]));
      asm("v_permlane32_swap_b32 %0, %1" : "+v"(X0), "+v"(Y0));
      asm("v_permlane32_swap_b32 %0, %1" : "+v"(X1), "+v"(Y1));
      UP4 P;
      P.u[0] = X0; P.u[1] = X1; P.u[2] = Y0; P.u[3] = Y1;
      pa[ks] = P.v;
    }
#pragma unroll
    for (int n = 0; n < 4; ++n) {
      unsigned long long t0[4], t1[4];
#pragma unroll
      for (int ks = 0; ks < 4; ++ks) {
        unsigned int addr = vbase
          + (unsigned int)(((4 * ks + 2 * hi) * 8 + 2 * n + ((lane >> 4) & 1)) * 128)
          + (unsigned int)((lane & 15) * 8);
        asm volatile("ds_read_b64_tr_b16 %0, %1" : "=v"(t0[ks]) : "v"(addr));
        asm volatile("ds_read_b64_tr_b16 %0, %1 offset:1024" : "=v"(t1[ks]) : "v"(addr));
      }
      asm volatile("s_waitcnt lgkmcnt(0)" ::: "memory");
      __builtin_amdgcn_sched_barrier(0);
#pragma unroll
      for (int ks = 0; ks < 4; ++ks) {
        union { unsigned long long q[2]; short8 v; } vb;
        vb.q[0] = t0[ks]; vb.q[1] = t1[ks];
        acc[n] = __builtin_amdgcn_mfma_f32_32x32x16_bf16(pa[ks], vb.v, acc[n], 0, 0, 0);
      }
    }
  }

  if (L == 0.0f) L = 1.0f;
  float rinv = 1.0f / L;
#pragma unroll
  for (int r = 0; r < 16; ++r) {
    int cr = (r & 3) + 8 * (r >> 2) + 4 * hi;
    float inv = __shfl(rinv, cr);
    float* op = outg + ((size_t)b * SQ + (q0 + w * 32 + cr)) * DM + h * DH + ql;
    op[0]  = acc[0][r] * inv;
    op[32] = acc[1][r] * inv;
    op[64] = acc[2][r] * inv;
    op[96] = acc[3][r] * inv;
  }
}

extern "C" void kernel_launch(void* const* d_in, const int* in_sizes, int n_in,
                              void* d_out, int out_size, void* d_ws, size_t ws_size,
                              hipStream_t stream) {
  (void)in_sizes; (void)n_in; (void)out_size;
  const float* q = (const float*)d_in[0];
  const float* k = (const float*)d_in[1];
  const float* v = (const float*)d_in[2];
  const unsigned char* mask = (const unsigned char*)d_in[3];
  const int* qs = (const int*)d_in[4];

  const size_t need = (size_t)2 * 16777216 * 2;   // K + V bf16 = 64 MiB
  if (ws_size >= need) {
    unsigned short* kws = (unsigned short*)d_ws;
    unsigned short* vws = kws + 16777216;
    dim3 pgrid(NT, 16, 4);
    eit3_pre<<<pgrid, dim3(512), 0, stream>>>(k, v, kws, vws);
    eit3_attn<<<dim3(1024), dim3(256), 0, stream>>>(kws, vws, q, mask, qs, (float*)d_out);
  } else {
    dim3 grid(SQ / 256, 16, 4);
    eit3_attn_fb<<<grid, dim3(512), 0, stream>>>(q, k, v, mask, qs, (float*)d_out);
  }
}

// Round 7
// 220.635 us; speedup vs baseline: 1.0397x; 1.0397x over previous
//
#include <hip/hip_runtime.h>

// EIT3Attention: B=4, Sq=Sk=2048, d_model=2048, H=16, Dh=128, fp32 I/O.
// R7 = R6 + T15 software pipeline: triple-buffered LDS (stage distance 2),
// iteration t issues QK^T(t+1) BEFORE softmax(t) so the softmax VALU chain
// (~400 cyc) overlaps the independent QK^T MFMA chain. Manual 2-step unroll
// (static stA/stB names), rotating buffer indices in scalar regs.
// R6 counters: Mfma 28% + VALU 42% additive, both pipes underused -> serial
// per-tile chain was the binding constraint.

typedef __attribute__((ext_vector_type(8))) short short8;
typedef __attribute__((ext_vector_type(16))) float f32x16;

#define DEVI __device__ __forceinline__

namespace {

constexpr int DM = 2048;   // d_model
constexpr int SQ = 2048;
constexpr int SK = 2048;
constexpr int DH = 128;
constexpr int KVB = 32;            // kv rows per tile
constexpr int NT = SK / KVB;       // 64 tiles
constexpr int TILE_E = KVB * DH;   // 4096 elems per tensor-tile
// (1/sqrt(128)) * log2(e)
constexpr float CEXP = 0.12752051393f;
constexpr float DEFER = 62.0f;     // raw-score defer threshold (~e^7.9 bound)

union US8 { unsigned short u[8]; short8 v; };
union UP4 { unsigned int u[4]; short8 v; };

DEVI unsigned short f2bf(float f) {            // fp32 -> bf16 RNE
  unsigned int u = __float_as_uint(f);
  return (unsigned short)((u + 0x7fffu + ((u >> 16) & 1u)) >> 16);
}

DEVI float dq(float x) {                       // int4 quant-dequant, matches ref
  float t = __builtin_rintf(__builtin_fmaf(x, 20.0f, 8.0f));  // round half-even
  t = __builtin_fmaxf(t, 0.0f);
  t = __builtin_fminf(t, 15.0f);
  return (t - 8.0f) * 0.05f;
}

DEVI unsigned short dqb(float x) { return f2bf(dq(x)); }

} // namespace

// ---------------------------------------------------------------------------
// Prepass (verified R2/R3/R6): dequant K/V -> bf16 ws, one (b,h,32-row-tile)/blk.
// K ws tile: elem u = (n*128 + d) ^ ((n&7)<<3)            [n=0..31, d=0..127]
// V ws tile: transposed, elem u = d*32 + (k ^ (((d>>1)&3)<<3))    [k=0..31]
// Both are the exact linear LDS images the main kernel stages + reads.
// ---------------------------------------------------------------------------
__global__ __launch_bounds__(512)
void eit3_pre(const float* __restrict__ kg, const float* __restrict__ vg,
              unsigned short* __restrict__ kws, unsigned short* __restrict__ vws)
{
  const int tid = threadIdx.x;
  const int t = blockIdx.x, h = blockIdx.y, b = blockIdx.z;
  const size_t tb = (((size_t)(b * 16 + h)) * NT + t) * TILE_E;
  // V transpose staging: stride 132 elems; granule col of (r,*) ^= ((r>>3)&3)
  __shared__ __align__(16) unsigned short VL[32 * 132];

  // ---- K: dest-driven (swizzle is self-inverse on the d field) ----
  {
    const int g = tid;                      // 512 granules of 8 elems
    const int n = g >> 4;
    const int dsw = ((g & 15) * 8) ^ ((n & 7) << 3);
    const float* src = kg + ((size_t)b * SK + (size_t)t * KVB + n) * DM + h * DH + dsw;
    float4 fa = *(const float4*)src;
    float4 fb = *(const float4*)(src + 4);
    US8 o;
    o.u[0] = dqb(fa.x); o.u[1] = dqb(fa.y); o.u[2] = dqb(fa.z); o.u[3] = dqb(fa.w);
    o.u[4] = dqb(fb.x); o.u[5] = dqb(fb.y); o.u[6] = dqb(fb.z); o.u[7] = dqb(fb.w);
    *(short8*)(kws + tb + (size_t)g * 8) = o.v;
  }
  // ---- V rows -> LDS (dequant, coalesced read, swizzled column granule) ----
  {
    const int r = tid >> 4, dg = tid & 15;
    const float* src = vg + ((size_t)b * SK + (size_t)t * KVB + r) * DM + h * DH + dg * 8;
    float4 fa = *(const float4*)src;
    float4 fb = *(const float4*)(src + 4);
    US8 o;
    o.u[0] = dqb(fa.x); o.u[1] = dqb(fa.y); o.u[2] = dqb(fa.z); o.u[3] = dqb(fa.w);
    o.u[4] = dqb(fb.x); o.u[5] = dqb(fb.y); o.u[6] = dqb(fb.z); o.u[7] = dqb(fb.w);
    *(short8*)(VL + r * 132 + (dg ^ ((r >> 3) & 3)) * 8) = o.v;
  }
  __syncthreads();
  // ---- V^T: dest-driven transpose out of LDS, coalesced 16B ws writes ----
  {
    const int g2 = tid;                 // dest granules [g2*8, g2*8+8)
    const int d = g2 >> 2;
    const int kgr = (g2 & 3) ^ ((d >> 1) & 3);
    US8 o;
#pragma unroll
    for (int i = 0; i < 8; ++i) {
      int r = kgr * 8 + i;
      o.u[i] = VL[r * 132 + (d ^ (kgr * 8))];
    }
    *(short8*)(vws + tb + (size_t)g2 * 8) = o.v;
  }
}

// ---------------------------------------------------------------------------
// Main attention kernel: 4 waves, 32 q-rows/wave, KVB=32, triple-buffered,
// QK^T(t+1) || softmax(t) software pipeline.
// ---------------------------------------------------------------------------
__global__ __launch_bounds__(256, 2)
void eit3_attn(const unsigned short* __restrict__ kws,
               const unsigned short* __restrict__ vws,
               const float* __restrict__ qg,
               const unsigned char* __restrict__ maskg,
               const int* __restrict__ qsg, float* __restrict__ outg)
{
  const int tid  = threadIdx.x;
  const int lane = tid & 63;
  const int w    = tid >> 6;        // wave 0..3
  const int hi   = lane >> 5;
  const int ql   = lane & 31;
  const int hi8  = hi * 8;
  // XCD-grouped decode: XCD x owns bh in {8g+x}; 16 q-blocks of a bh + 8 bh
  // co-located per XCD -> ws streams are L2 hits after first touch.
  const int phys = blockIdx.x;                     // 0..1023
  const int xcd = phys & 7, slot = phys >> 3;      // slot 0..127
  const int bh = 8 * (slot >> 4) + xcd;            // 0..63
  const int qb = slot & 15;                        // 0..15
  const int h = bh & 15, b = bh >> 4;
  const int q0 = qb * 128;
  const long long qstart = (long long)qsg[0];

  __shared__ __align__(16) unsigned short Ksh[3][TILE_E];
  __shared__ __align__(16) unsigned short Vsh[3][TILE_E];
  __shared__ unsigned char mskSh[3][32];

  // ---- robust all-true mask check (u8 or i32 bool layouts), 8 B/thread ----
  const unsigned char* mrow = maskg + (size_t)b * SK;
  int ok_u8, ok_i32;
  {
    const unsigned int* p = (const unsigned int*)(mrow + tid * 8);
    unsigned int w0 = p[0], w1 = p[1];
    int a0 = (w0 & 0xFFu) && (w0 & 0xFF00u) && (w0 & 0xFF0000u) && (w0 & 0xFF000000u);
    int a1 = (w1 & 0xFFu) && (w1 & 0xFF00u) && (w1 & 0xFF0000u) && (w1 & 0xFF000000u);
    ok_u8  = a0 && a1;
    ok_i32 = (w0 == 1u) && (w1 == 1u);
  }
  const int a_u8  = __syncthreads_and(ok_u8);
  const int a_i32 = __syncthreads_and(ok_i32);
  const bool mask_all = (a_u8 | a_i32) != 0;

  const size_t tbase = (size_t)bh * NT * TILE_E;

  // stage tile t into buffer buf: 1 KiB per wave per tensor = 2 gll each
  auto stage = [&](int buf, int t) {
    const unsigned short* kt = kws + tbase + (size_t)t * TILE_E + w * 1024 + lane * 8;
    const unsigned short* vt = vws + tbase + (size_t)t * TILE_E + w * 1024 + lane * 8;
    char* kd = (char*)&Ksh[0][0] + buf * 8192 + w * 2048;
    char* vd = (char*)&Vsh[0][0] + buf * 8192 + w * 2048;
    __builtin_amdgcn_global_load_lds(
        (const __attribute__((address_space(1))) void*)kt,
        (__attribute__((address_space(3))) void*)kd, 16, 0, 0);
    __builtin_amdgcn_global_load_lds(
        (const __attribute__((address_space(1))) void*)(kt + 512),
        (__attribute__((address_space(3))) void*)(kd + 1024), 16, 0, 0);
    __builtin_amdgcn_global_load_lds(
        (const __attribute__((address_space(1))) void*)vt,
        (__attribute__((address_space(3))) void*)vd, 16, 0, 0);
    __builtin_amdgcn_global_load_lds(
        (const __attribute__((address_space(1))) void*)(vt + 512),
        (__attribute__((address_space(3))) void*)(vd + 1024), 16, 0, 0);
  };

  stage(0, 0);   // prologue: stage tiles 0 and 1 before Q loads
  stage(1, 1);

  // ---- Q fragments (B-operand of swapped QK^T): lane holds Q[q][16s+8hi+i] ----
  short8 qf[8];
  {
    const float* qp = qg + ((size_t)b * SQ + q0 + w * 32 + ql) * DM + h * DH + hi8;
#pragma unroll
    for (int s = 0; s < 8; ++s) {
      float4 fa = *(const float4*)(qp + s * 16);
      float4 fb = *(const float4*)(qp + s * 16 + 4);
      US8 t;
      t.u[0] = f2bf(fa.x); t.u[1] = f2bf(fa.y); t.u[2] = f2bf(fa.z); t.u[3] = f2bf(fa.w);
      t.u[4] = f2bf(fb.x); t.u[5] = f2bf(fb.y); t.u[6] = f2bf(fb.z); t.u[7] = f2bf(fb.w);
      qf[s] = t.v;
    }
  }

  f32x16 zv;
#pragma unroll
  for (int r = 0; r < 16; ++r) zv[r] = 0.0f;
  f32x16 acc[4];
  acc[0] = zv; acc[1] = zv; acc[2] = zv; acc[3] = zv;
  float M = -3.0e38f, L = 0.0f;
  const long long qlim = qstart + (long long)(q0 + w * 32 + ql);

  // QK^T for one tile from LDS buffer Kc into out (independent MFMA chain)
  auto qkt = [&](const unsigned short* Kc, f32x16& out) {
    f32x16 sa = zv;
#pragma unroll
    for (int s = 0; s < 8; ++s) {
      short8 af = *(const short8*)(Kc + ql * 128 + ((s * 16 + hi8) ^ ((ql & 7) << 3)));
      sa = __builtin_amdgcn_mfma_f32_32x32x16_bf16(af, qf[s], sa, 0, 0, 0);
    }
    out = sa;
  };

  // masks for tiles 0,1 (slow path only)
  {
    bool f0 = mask_all && ((long long)(KVB - 1) <= qstart + (long long)q0);
    if (!f0 && w == 0 && lane < 32) mskSh[0][lane] = mrow[lane];
    bool f1 = mask_all && ((long long)(2 * KVB - 1) <= qstart + (long long)q0);
    if (!f1 && w == 0 && lane < 32) mskSh[1][lane] = mrow[KVB + lane];
  }
  __syncthreads();   // drains stage(0)/stage(1) vmcnt

  f32x16 stA, stB;
  qkt(&Ksh[0][0], stA);        // scores for tile 0

  // one pipeline step: softmax+PV on tile t (scores in stP, buffers b0),
  // QK^T(t+1) from b1 into stN, stage tile t+2 into b2.
  auto step = [&](int t, f32x16& stP, f32x16& stN, int b0, int b1, int b2) {
    const int kv0 = t * KVB;
    if (t + 2 < NT) {
      stage(b2, t + 2);
      bool fn = mask_all && ((long long)(kv0 + 3 * KVB - 1) <= qstart + (long long)q0);
      if (!fn && w == 0 && lane < 32) mskSh[b2][lane] = mrow[kv0 + 2 * KVB + lane];
    }
    if (t + 1 < NT) qkt(&Ksh[b1][0], stN);   // overlaps softmax(t) below

    const bool fast = mask_all && ((long long)(kv0 + KVB - 1) <= qstart + (long long)q0);

    // ---- masking (slow path only) ----
    if (!fast) {
#pragma unroll
      for (int r = 0; r < 16; ++r) {
        int nl = (r & 3) + 8 * (r >> 2) + 4 * hi;
        bool ok = (mskSh[b0][nl] != 0) && ((long long)(kv0 + nl) <= qlim);
        if (!ok) stP[r] = -3.0e38f;
      }
    }

    // ---- online softmax (defer-max); verified shfl_xor pair reduce ----
    float t8[8];
#pragma unroll
    for (int i = 0; i < 8; ++i) t8[i] = __builtin_fmaxf(stP[i], stP[i + 8]);
#pragma unroll
    for (int i = 0; i < 4; ++i) t8[i] = __builtin_fmaxf(t8[i], t8[i + 4]);
    float pmax = __builtin_fmaxf(__builtin_fmaxf(t8[0], t8[1]),
                                 __builtin_fmaxf(t8[2], t8[3]));
    pmax = __builtin_fmaxf(pmax, __shfl_xor(pmax, 32));
    if (!__all(pmax <= M + DEFER)) {        // T13: rescale only on real growth
      float Mn = __builtin_fmaxf(M, pmax);
      float sc = __builtin_amdgcn_exp2f((M - Mn) * CEXP);
      L *= sc;
#pragma unroll
      for (int r = 0; r < 16; ++r) {
        float s2 = __shfl(sc, (r & 3) + 8 * (r >> 2) + 4 * hi);
        acc[0][r] *= s2; acc[1][r] *= s2; acc[2][r] *= s2; acc[3][r] *= s2;
      }
      M = Mn;
    }
#pragma unroll
    for (int r = 0; r < 16; ++r)
      stP[r] = __builtin_amdgcn_exp2f((stP[r] - M) * CEXP);
    if (!fast) {   // force masked p to exactly 0 (handles all-masked tiles)
#pragma unroll
      for (int r = 0; r < 16; ++r) {
        int nl = (r & 3) + 8 * (r >> 2) + 4 * hi;
        bool ok = (mskSh[b0][nl] != 0) && ((long long)(kv0 + nl) <= qlim);
        if (!ok) stP[r] = 0.0f;
      }
    }
    float s8[8];
#pragma unroll
    for (int i = 0; i < 8; ++i) s8[i] = stP[i] + stP[i + 8];
#pragma unroll
    for (int i = 0; i < 4; ++i) s8[i] = s8[i] + s8[i + 4];
    float ps = (s8[0] + s8[1]) + (s8[2] + s8[3]);
    ps += __shfl_xor(ps, 32);
    L += ps;

    // ---- P -> bf16 A-frags: cvt_pk pairs + permlane32_swap (T12) ----
    // (safe: X*/Y* hold DISTINCT values, no register-coalescing hazard)
    short8 pa[2];
#pragma unroll
    for (int ks = 0; ks < 2; ++ks) {
      const int m8 = ks * 8;
      unsigned int X0, X1, Y0, Y1;
      asm("v_cvt_pk_bf16_f32 %0, %1, %2" : "=v"(X0) : "v"(stP[m8 + 0]), "v"(stP[m8 + 1]));
      asm("v_cvt_pk_bf16_f32 %0, %1, %2" : "=v"(X1) : "v"(stP[m8 + 2]), "v"(stP[m8 + 3]));
      asm("v_cvt_pk_bf16_f32 %0, %1, %2" : "=v"(Y0) : "v"(stP[m8 + 4]), "v"(stP[m8 + 5]));
      asm("v_cvt_pk_bf16_f32 %0, %1, %2" : "=v"(Y1) : "v"(stP[m8 + 6]), "v"(stP[m8 + 7]));
      asm("v_permlane32_swap_b32 %0, %1" : "+v"(X0), "+v"(Y0));
      asm("v_permlane32_swap_b32 %0, %1" : "+v"(X1), "+v"(Y1));
      UP4 P;
      P.u[0] = X0; P.u[1] = X1; P.u[2] = Y0; P.u[3] = Y1;
      pa[ks] = P.v;
    }

    // ---- PV: out[q][d] += P[q][k]·Vd[k][d]; B-frag from V^T LDS ----
    const unsigned short* Vc = &Vsh[b0][0];
    __builtin_amdgcn_s_setprio(1);
#pragma unroll
    for (int n = 0; n < 4; ++n) {
      const unsigned short* vrow = Vc + n * 1024 + ql * 32;
#pragma unroll
      for (int ks = 0; ks < 2; ++ks) {
        short8 vb = *(const short8*)(vrow + ((ks * 16 + hi8) ^ (((ql >> 1) & 3) << 3)));
        acc[n] = __builtin_amdgcn_mfma_f32_32x32x16_bf16(pa[ks], vb, acc[n], 0, 0, 0);
      }
    }
    __builtin_amdgcn_s_setprio(0);

    __syncthreads();   // reads of b0/b1 done + stage(b2) vmcnt drained
  };

  int bA = 0, bB = 1, bC = 2;   // buffers of tiles t, t+1, t+2 (scalar regs)
  for (int t = 0; t < NT; t += 2) {
    step(t,     stA, stB, bA, bB, bC);
    step(t + 1, stB, stA, bB, bC, bA);
    int tmp = bA; bA = bC; bC = bB; bB = tmp;   // net rotation by 2
  }

  // ---- epilogue: out = acc / L ----
  if (L == 0.0f) L = 1.0f;
  float rinv = 1.0f / L;
#pragma unroll
  for (int r = 0; r < 16; ++r) {
    int cr = (r & 3) + 8 * (r >> 2) + 4 * hi;
    float inv = __shfl(rinv, cr);
    float* op = outg + ((size_t)b * SQ + q0 + w * 32 + cr) * DM + h * DH + ql;
    op[0]  = acc[0][r] * inv;
    op[32] = acc[1][r] * inv;
    op[64] = acc[2][r] * inv;
    op[96] = acc[3][r] * inv;
  }
}

// ---------------------------------------------------------------------------
// Fallback (R1 kernel, in-kernel dequant) — used only if ws is too small.
// ---------------------------------------------------------------------------
__global__ __launch_bounds__(512, 2)
void eit3_attn_fb(const float* __restrict__ qg, const float* __restrict__ kg,
                  const float* __restrict__ vg, const unsigned char* __restrict__ maskg,
                  const int* __restrict__ qsg, float* __restrict__ outg)
{
  const int tid  = threadIdx.x;
  const int lane = tid & 63;
  const int w    = tid >> 6;
  const int hi   = lane >> 5;
  const int ql   = lane & 31;
  const int qb = blockIdx.x;
  const int h  = blockIdx.y;
  const int b  = blockIdx.z;
  const int q0 = qb * 256;
  const long long qstart = (long long)qsg[0];

  __shared__ __align__(16) unsigned short Ksh[64 * 128];
  __shared__ __align__(16) unsigned short Vsh[64 * 128];
  __shared__ unsigned char mskSh[64];

  const unsigned int vbase = (unsigned int)(size_t)(void*)Vsh;

  const unsigned char* mrow = maskg + (size_t)b * SK;
  int ok_u8, ok_i32;
  {
    const unsigned char* p4 = mrow + tid * 4;
    unsigned char b0 = p4[0], b1 = p4[1], b2 = p4[2], b3 = p4[3];
    ok_u8  = (b0 && b1 && b2 && b3);
    ok_i32 = (b0 && !b1 && !b2 && !b3);
  }
  const int a_u8  = __syncthreads_and(ok_u8);
  const int a_i32 = __syncthreads_and(ok_i32);
  const bool mask_all = (a_u8 | a_i32) != 0;

  short8 qf[8];
  {
    const int qrow = q0 + w * 32 + ql;
    const float* qp = qg + ((size_t)b * SQ + qrow) * DM + h * DH + hi * 8;
#pragma unroll
    for (int s = 0; s < 8; ++s) {
      float4 fa = *(const float4*)(qp + s * 16);
      float4 fb = *(const float4*)(qp + s * 16 + 4);
      US8 t;
      t.u[0] = f2bf(fa.x); t.u[1] = f2bf(fa.y); t.u[2] = f2bf(fa.z); t.u[3] = f2bf(fa.w);
      t.u[4] = f2bf(fb.x); t.u[5] = f2bf(fb.y); t.u[6] = f2bf(fb.z); t.u[7] = f2bf(fb.w);
      qf[s] = t.v;
    }
  }

  f32x16 zv;
#pragma unroll
  for (int r = 0; r < 16; ++r) zv[r] = 0.0f;
  f32x16 acc[4];
  acc[0] = zv; acc[1] = zv; acc[2] = zv; acc[3] = zv;
  float M = -3.0e38f, L = 0.0f;

  const float* kptr = kg + ((size_t)b * SK) * DM + h * DH;
  const float* vptr = vg + ((size_t)b * SK) * DM + h * DH;

  for (int kv0 = 0; kv0 < SK; kv0 += 64) {
    __syncthreads();
#pragma unroll
    for (int j = 0; j < 2; ++j) {
      int idx = tid + 512 * j;
      int n = idx >> 4, d8 = idx & 15;
      const float* gp = kptr + (size_t)(kv0 + n) * DM + d8 * 8;
      float4 fa = *(const float4*)gp;
      float4 fb = *(const float4*)(gp + 4);
      US8 t;
      t.u[0] = dqb(fa.x); t.u[1] = dqb(fa.y); t.u[2] = dqb(fa.z); t.u[3] = dqb(fa.w);
      t.u[4] = dqb(fb.x); t.u[5] = dqb(fb.y); t.u[6] = dqb(fb.z); t.u[7] = dqb(fb.w);
      int ui = (n * 128 + d8 * 8) ^ ((n & 7) << 3);
      *(short8*)(Ksh + ui) = t.v;
    }
    {
      int kr = w * 8 + (lane & 7);
      int c3 = lane >> 3;
#pragma unroll
      for (int j = 0; j < 4; ++j) {
        int d4 = c3 + 8 * j;
        const float* gp = vptr + (size_t)(kv0 + kr) * DM + d4 * 4;
        float4 fa = *(const float4*)gp;
        ushort4 tv;
        tv.x = dqb(fa.x); tv.y = dqb(fa.y); tv.z = dqb(fa.z); tv.w = dqb(fa.w);
        int d = d4 * 4;
        int ui = ((kr >> 2) * 8 + (d >> 4)) * 64 + (kr & 3) * 16 + (d & 15);
        *(ushort4*)(Vsh + ui) = tv;
      }
    }
    const bool causal_ok = ((long long)kv0 + 63) <= (qstart + (long long)q0);
    const bool fast = mask_all && causal_ok;
    if (!fast && w == 0) mskSh[lane] = mrow[kv0 + lane];
    __syncthreads();

    f32x16 st[2];
#pragma unroll
    for (int t = 0; t < 2; ++t) {
      f32x16 sa = zv;
#pragma unroll
      for (int s = 0; s < 8; ++s) {
        int kr = t * 32 + ql;
        int ui = (kr * 128 + s * 16 + hi * 8) ^ ((kr & 7) << 3);
        short8 af = *(const short8*)(Ksh + ui);
        sa = __builtin_amdgcn_mfma_f32_32x32x16_bf16(af, qf[s], sa, 0, 0, 0);
      }
      st[t] = sa;
    }
    if (!fast) {
      const long long qlim = qstart + (long long)(q0 + w * 32 + ql);
#pragma unroll
      for (int t = 0; t < 2; ++t) {
#pragma unroll
        for (int r = 0; r < 16; ++r) {
          int nl = t * 32 + (r & 3) + 8 * (r >> 2) + 4 * hi;
          bool ok = (mskSh[nl] != 0) && ((long long)(kv0 + nl) <= qlim);
          if (!ok) st[t][r] = -3.0e38f;
        }
      }
    }
    f32x16 red;
#pragma unroll
    for (int r = 0; r < 16; ++r) red[r] = __builtin_fmaxf(st[0][r], st[1][r]);
#pragma unroll
    for (int r = 0; r < 8; ++r) red[r] = __builtin_fmaxf(red[r], red[r + 8]);
#pragma unroll
    for (int r = 0; r < 4; ++r) red[r] = __builtin_fmaxf(red[r], red[r + 4]);
    float pmax = __builtin_fmaxf(__builtin_fmaxf(red[0], red[1]),
                                 __builtin_fmaxf(red[2], red[3]));
    pmax = __builtin_fmaxf(pmax, __shfl_xor(pmax, 32));
    const float Mnew = __builtin_fmaxf(M, pmax);
    const float scale = __builtin_amdgcn_exp2f((M - Mnew) * CEXP);
#pragma unroll
    for (int t = 0; t < 2; ++t) {
#pragma unroll
      for (int r = 0; r < 16; ++r)
        st[t][r] = __builtin_amdgcn_exp2f((st[t][r] - Mnew) * CEXP);
    }
    if (!fast) {
      const long long qlim = qstart + (long long)(q0 + w * 32 + ql);
#pragma unroll
      for (int t = 0; t < 2; ++t) {
#pragma unroll
        for (int r = 0; r < 16; ++r) {
          int nl = t * 32 + (r & 3) + 8 * (r >> 2) + 4 * hi;
          bool ok = (mskSh[nl] != 0) && ((long long)(kv0 + nl) <= qlim);
          if (!ok) st[t][r] = 0.0f;
        }
      }
    }
    f32x16 sx;
#pragma unroll
    for (int r = 0; r < 16; ++r) sx[r] = st[0][r] + st[1][r];
#pragma unroll
    for (int r = 0; r < 8; ++r) sx[r] = sx[r] + sx[r + 8];
#pragma unroll
    for (int r = 0; r < 4; ++r) sx[r] = sx[r] + sx[r + 4];
    float ps = (sx[0] + sx[1]) + (sx[2] + sx[3]);
    ps += __shfl_xor(ps, 32);
    L = L * scale + ps;
    if (!__all(Mnew == M)) {
#pragma unroll
      for (int r = 0; r < 16; ++r) {
        float sc = __shfl(scale, (r & 3) + 8 * (r >> 2) + 4 * hi);
        acc[0][r] *= sc; acc[1][r] *= sc; acc[2][r] *= sc; acc[3][r] *= sc;
      }
    }
    M = Mnew;

    short8 pa[4];
#pragma unroll
    for (int ks = 0; ks < 4; ++ks) {
      const int t = ks >> 1;
      const int m8 = (ks & 1) * 8;
      unsigned int X0, X1, Y0, Y1;
      asm("v_cvt_pk_bf16_f32 %0, %1, %2" : "=v"(X0) : "v"(st[t][m8 + 0]), "v"(st[t][m8 + 1]));
      asm("v_cvt_pk_bf16_f32 %0, %1, %2" : "=v"(X1) : "v"(st[t][m8 + 2]), "v"(st[t][m8 + 3]));
      asm("v_cvt_pk_bf16_f32 %0, %1, %2" : "=v"(Y0) : "v"(st[t][m8 + 4]), "v"(st[t][m8 + 5]));
      asm("v_cvt_pk_bf16_f32 %0, %1, %2" : "=v"(Y1) : "v"(st[t][m8 + 6]), "v"(st[t][m8 + 7]));
      asm("v_permlane32_swap_b32 %0, %1" : "+v"(X0), "+v"(Y0));
      asm("v_permlane32_swap_b32 %0, %1" : "+v"(X1), "+v"(Y1));
      UP4 P;
      P.u[0] = X0; P.u[1] = X1; P.u[2] = Y0; P.u[3] = Y1;
      pa[ks] = P.v;
    }
#pragma unroll
    for (int n = 0; n < 4; ++n) {
      unsigned long long t0[4], t1[4];
#pragma unroll
      for (int ks = 0; ks < 4; ++ks) {
        unsigned int addr = vbase
          + (unsigned int)(((4 * ks + 2 * hi) * 8 + 2 * n + ((lane >> 4) & 1)) * 128)
          + (unsigned int)((lane & 15) * 8);
        asm volatile("ds_read_b64_tr_b16 %0, %1" : "=v"(t0[ks]) : "v"(addr));
        asm volatile("ds_read_b64_tr_b16 %0, %1 offset:1024" : "=v"(t1[ks]) : "v"(addr));
      }
      asm volatile("s_waitcnt lgkmcnt(0)" ::: "memory");
      __builtin_amdgcn_sched_barrier(0);
#pragma unroll
      for (int ks = 0; ks < 4; ++ks) {
        union { unsigned long long q[2]; short8 v; } vb;
        vb.q[0] = t0[ks]; vb.q[1] = t1[ks];
        acc[n] = __builtin_amdgcn_mfma_f32_32x32x16_bf16(pa[ks], vb.v, acc[n], 0, 0, 0);
      }
    }
  }

  if (L == 0.0f) L = 1.0f;
  float rinv = 1.0f / L;
#pragma unroll
  for (int r = 0; r < 16; ++r) {
    int cr = (r & 3) + 8 * (r >> 2) + 4 * hi;
    float inv = __shfl(rinv, cr);
    float* op = outg + ((size_t)b * SQ + (q0 + w * 32 + cr)) * DM + h * DH + ql;
    op[0]  = acc[0][r] * inv;
    op[32] = acc[1][r] * inv;
    op[64] = acc[2][r] * inv;
    op[96] = acc[3][r] * inv;
  }
}

extern "C" void kernel_launch(void* const* d_in, const int* in_sizes, int n_in,
                              void* d_out, int out_size, void* d_ws, size_t ws_size,
                              hipStream_t stream) {
  (void)in_sizes; (void)n_in; (void)out_size;
  const float* q = (const float*)d_in[0];
  const float* k = (const float*)d_in[1];
  const float* v = (const float*)d_in[2];
  const unsigned char* mask = (const unsigned char*)d_in[3];
  const int* qs = (const int*)d_in[4];

  const size_t need = (size_t)2 * 16777216 * 2;   // K + V bf16 = 64 MiB
  if (ws_size >= need) {
    unsigned short* kws = (unsigned short*)d_ws;
    unsigned short* vws = kws + 16777216;
    dim3 pgrid(NT, 16, 4);
    eit3_pre<<<pgrid, dim3(512), 0, stream>>>(k, v, kws, vws);
    eit3_attn<<<dim3(1024), dim3(256), 0, stream>>>(kws, vws, q, mask, qs, (float*)d_out);
  } else {
    dim3 grid(SQ / 256, 16, 4);
    eit3_attn_fb<<<grid, dim3(512), 0, stream>>>(q, k, v, mask, qs, (float*)d_out);
  }
}